// Round 16
// baseline (495.735 us; speedup 1.0000x reference)
//
#include <hip/hip_runtime.h>
#include <stdint.h>

// FuncSelfAttention: b=4, s=256, E=256, H=8, d=32, p=16x16=256
// Round 16 = round 15 (== round 13, 488 us verified) + k_avT grid relabel:
//   bid = nsl*32 + bh  (was bh*16 + nsl).  The 16 blocks sharing one bh now
//   sit at bids == bh (mod 8) -> same XCD -> the 128 KB P[bh] A-slice is
//   L2-resident after the first block instead of ~8 HBM fetches.
//
// d_out: Qb 128MiB | Kb 128MiB (dead before k_outT writes 256MiB f32 at base)
// d_ws : Vt 128MiB | R 128MiB (seqT -> Sp -> SAT) | Pb 4MiB | Wbf 0.5MiB

#define DI __device__ __forceinline__

typedef __attribute__((ext_vector_type(4))) float  f32x4;
typedef __attribute__((ext_vector_type(8))) short  s16x8;
typedef __attribute__((ext_vector_type(4))) short  s16x4;
typedef __attribute__((ext_vector_type(8))) __bf16 bf16x8;

DI unsigned short f2bf(float f) {
    unsigned int u = __builtin_bit_cast(unsigned int, f);
    u = (u + 0x7fffu + ((u >> 16) & 1u)) >> 16;
    return (unsigned short)u;
}
DI bf16x8 asbf(s16x8 v) { return __builtin_bit_cast(bf16x8, v); }
#define MFMA16(a, b, c) __builtin_amdgcn_mfma_f32_16x16x32_bf16((a), (b), (c), 0, 0, 0)

#define GLOAD16(g, l) __builtin_amdgcn_global_load_lds( \
    (const __attribute__((address_space(1))) unsigned int*)(g), \
    (__attribute__((address_space(3))) unsigned int*)(l), 16, 0, 0)

#define WAIT_VM(N) asm volatile("s_waitcnt vmcnt(" #N ")" ::: "memory")
#define BAR()    __builtin_amdgcn_s_barrier()
#define SCHED0() __builtin_amdgcn_sched_barrier(0)
#define PRIO1()  __builtin_amdgcn_s_setprio(1)
#define PRIO0()  __builtin_amdgcn_s_setprio(0)

// ===========================================================================
// Stream-GEMM building blocks
// ===========================================================================

DI void sgk_loadA4(const unsigned short* __restrict__ Asrc,
                   s16x8 af[4][8], int wm, int lg, int lr) {
#pragma unroll
    for (int m = 0; m < 4; m++)
#pragma unroll
        for (int kf = 0; kf < 8; kf++)
            af[m][kf] = *(const s16x8*)(Asrc + (size_t)(wm + m * 16 + lr) * 256
                                        + kf * 32 + lg * 8);
}
DI void sgk_loadA2(const unsigned short* __restrict__ Asrc,
                   s16x8 af[2][8], int wm, int lg, int lr) {
#pragma unroll
    for (int m = 0; m < 2; m++)
#pragma unroll
        for (int kf = 0; kf < 8; kf++)
            af[m][kf] = *(const s16x8*)(Asrc + (size_t)(wm + m * 16 + lr) * 256
                                        + kf * 32 + lg * 8);
}

// Stage one B-tile [64 n x 256 k] (32KB) with 512 threads: 4 gloads/thread.
DI void sgk_stage512(const unsigned short* src, size_t rstride,
                     unsigned short* lds, int tid) {
#pragma unroll
    for (int i = 0; i < 4; i++)
        GLOAD16(src + (size_t)(i * 16) * rstride, lds + ((i * 512 + tid) << 3));
}

DI void sgk_mfma4(const unsigned short* __restrict__ Bl,
                  const s16x8 af[4][8], f32x4 acc[4][4], int lg, int lr) {
    const f32x4 z4 = {0.f, 0.f, 0.f, 0.f};
    {
        s16x8 bfv[4];
#pragma unroll
        for (int n = 0; n < 4; n++)
            bfv[n] = *(const s16x8*)&Bl[(n * 16 + lr) * 256 + ((lg ^ (lr & 7)) << 3)];
#pragma unroll
        for (int n = 0; n < 4; n++) {
            bf16x8 bv = asbf(bfv[n]);
#pragma unroll
            for (int m = 0; m < 4; m++)
                acc[m][n] = MFMA16(asbf(af[m][0]), bv, z4);
        }
    }
#pragma unroll
    for (int kf = 1; kf < 8; kf++) {
        s16x8 bfv[4];
#pragma unroll
        for (int n = 0; n < 4; n++)
            bfv[n] = *(const s16x8*)&Bl[(n * 16 + lr) * 256
                                        + (((kf * 4 + lg) ^ (lr & 7)) << 3)];
#pragma unroll
        for (int n = 0; n < 4; n++) {
            bf16x8 bv = asbf(bfv[n]);
#pragma unroll
            for (int m = 0; m < 4; m++)
                acc[m][n] = MFMA16(asbf(af[m][kf]), bv, acc[m][n]);
        }
    }
}

DI void sgk_mfma2(const unsigned short* __restrict__ Bl,
                  const s16x8 af[2][8], f32x4 acc[2][4], int lg, int lr) {
    const f32x4 z4 = {0.f, 0.f, 0.f, 0.f};
    {
        s16x8 bfv[4];
#pragma unroll
        for (int n = 0; n < 4; n++)
            bfv[n] = *(const s16x8*)&Bl[(n * 16 + lr) * 256 + ((lg ^ (lr & 7)) << 3)];
#pragma unroll
        for (int n = 0; n < 4; n++) {
            bf16x8 bv = asbf(bfv[n]);
#pragma unroll
            for (int m = 0; m < 2; m++)
                acc[m][n] = MFMA16(asbf(af[m][0]), bv, z4);
        }
    }
#pragma unroll
    for (int kf = 1; kf < 8; kf++) {
        s16x8 bfv[4];
#pragma unroll
        for (int n = 0; n < 4; n++)
            bfv[n] = *(const s16x8*)&Bl[(n * 16 + lr) * 256
                                        + (((kf * 4 + lg) ^ (lr & 7)) << 3)];
#pragma unroll
        for (int n = 0; n < 4; n++) {
            bf16x8 bv = asbf(bfv[n]);
#pragma unroll
            for (int m = 0; m < 2; m++)
                acc[m][n] = MFMA16(asbf(af[m][kf]), bv, acc[m][n]);
        }
    }
}

#define SGK_SETUP()                                           \
    const int tid = threadIdx.x, ln = tid & 63, w = tid >> 6; \
    const int lg = ln >> 4, lr = ln & 15;                     \
    const size_t swoff = (size_t)(((tid & 31) ^ ((tid >> 5) & 7)) * 8); \
    const size_t srow = (size_t)(tid >> 5);

// ===========================================================================
// k_tr: seq f32 [bs][256 c][256 p] -> seqT bf16 [bs][256 p][256 c],
// PLUS prep of Wbf row r = blockIdx.x (W_qkv split-major permuted rows;
// W_out rows with columns permuted to SAT's channel order).
// ===========================================================================
__global__ __launch_bounds__(256) void k_tr(
    const float* __restrict__ seq, const float* __restrict__ Wqkv,
    const float* __restrict__ Wout, unsigned short* __restrict__ seqT,
    unsigned short* __restrict__ Wbf)
{
    const int bs = blockIdx.x, tid = threadIdx.x;

    {   // folded k_prep: one Wbf row per block, one element per thread
        int r = bs, c = tid;
        float v;
        if (r < 768) {
            int split = r >> 8, hd = r & 255;
            v = Wqkv[(size_t)(((hd >> 5) * 96) + split * 32 + (hd & 31)) * 256 + c];
        } else {
            int jj = c & 31;
            int dd = (jj >> 1) + ((jj & 1) << 4);   // inverse of (dd&15)*2+(dd>>4)
            v = Wout[(size_t)(r - 768) * 256 + (c & ~31) + dd];
        }
        Wbf[(size_t)r * 256 + c] = f2bf(v);
    }

    __shared__ __align__(16) unsigned short T[64][264];
    const float* src = seq + (size_t)bs * 65536;
    unsigned short* dst = seqT + (size_t)bs * 65536;

    for (int co = 0; co < 256; co += 64) {
        {
            int r = tid >> 2, p0 = (tid & 3) * 64;
            const float* s = src + (size_t)(co + r) * 256 + p0;
#pragma unroll
            for (int i = 0; i < 8; i++) {
                f32x4 a = *(const f32x4*)(s + i * 8);
                f32x4 b = *(const f32x4*)(s + i * 8 + 4);
                s16x8 h = {(short)f2bf(a.x), (short)f2bf(a.y), (short)f2bf(a.z),
                           (short)f2bf(a.w), (short)f2bf(b.x), (short)f2bf(b.y),
                           (short)f2bf(b.z), (short)f2bf(b.w)};
                *(s16x8*)&T[r][p0 + i * 8] = h;
            }
        }
        __syncthreads();
        {
            unsigned short e[64];
#pragma unroll
            for (int c = 0; c < 64; c++) e[c] = T[c][tid];
            unsigned short* d = dst + (size_t)tid * 256 + co;
#pragma unroll
            for (int j = 0; j < 8; j++) {
                s16x8 v = {(short)e[j * 8 + 0], (short)e[j * 8 + 1],
                           (short)e[j * 8 + 2], (short)e[j * 8 + 3],
                           (short)e[j * 8 + 4], (short)e[j * 8 + 5],
                           (short)e[j * 8 + 6], (short)e[j * 8 + 7]};
                *(s16x8*)(d + j * 8) = v;
            }
        }
        __syncthreads();
    }
}

// ===========================================================================
// k_proj: merged Q/K projection (bid < 256) and V projection (bid >= 256).
// QK: 8 waves x 64 rows (Q||K), 16 tiles, L=4 S=16 -> waits 4/20/16.
//     Q/K feature layout psw = pb + lr*4 + n.
// V : 8 waves x 32 rows, 8 tiles, L=4 S=8 -> waits 4/12/8.
//     Vt[bh][p*32+dd][ssw], ssw = sb + lr*4 + n (sigma-permuted s-axis).
// ===========================================================================
__global__ __launch_bounds__(512, 2) void k_proj(
    const unsigned short* __restrict__ seqT, const unsigned short* __restrict__ Wbf,
    unsigned short* __restrict__ Qb, unsigned short* __restrict__ Kb,
    unsigned short* __restrict__ Vt)
{
    __shared__ __align__(16) unsigned short Bb[2][16384];

    SGK_SETUP();

    if (blockIdx.x < 256) {
        // ---------------- QK path ----------------
        const int g = blockIdx.x;
        const int wm = w * 64;

        s16x8 af[4][8];
        sgk_loadA4(Wbf, af, wm, lg, lr);   // rows 0..511 = Q||K

        const unsigned short* Bsrc = seqT + (size_t)g * 262144 + srow * 256 + swoff;
        unsigned short* const dstB = (w >= 4) ? Kb : Qb;

        sgk_stage512(Bsrc, 256, Bb[0], tid);

        for (int t = 0; t < 16; t++) {
            if (t + 1 < 16)
                sgk_stage512(Bsrc + (size_t)(t + 1) * 16384, 256, Bb[(t + 1) & 1], tid);
            if (t == 0)      { WAIT_VM(4); }
            else if (t < 15) { WAIT_VM(20); }
            else             { WAIT_VM(16); }
            SCHED0(); BAR(); SCHED0();
            PRIO1();
            f32x4 acc[4][4];
            sgk_mfma4(Bb[t & 1], af, acc, lg, lr);
            PRIO0();

            const int bs = g * 4 + (t >> 2);
            const int b = bs >> 8, s = bs & 255;
            const int pb = (t & 3) * 64;
#pragma unroll
            for (int m = 0; m < 4; m++) {
#pragma unroll
                for (int rr = 0; rr < 4; rr++) {
                    int oo = wm + m * 16 + lg * 4 + rr;   // 0..511
                    int o = oo & 255;
                    size_t base = ((size_t)((b * 8 + (o >> 5)) * 256 + s)) * 8192
                                + (size_t)(o & 31) * 256 + pb + lr * 4;
                    s16x4 pk = {(short)f2bf(acc[m][0][rr]), (short)f2bf(acc[m][1][rr]),
                                (short)f2bf(acc[m][2][rr]), (short)f2bf(acc[m][3][rr])};
                    *(s16x4*)(dstB + base) = pk;
                }
            }
            SCHED0(); BAR(); SCHED0();
        }
    } else {
        // ---------------- V path ----------------
        const int x = blockIdx.x - 256;
        const int b = x >> 7, pg = x & 127;
        const int wm = w * 32;

        s16x8 af[2][8];
        sgk_loadA2(Wbf + 131072, af, wm, lg, lr);

        const unsigned short* Bsrc = seqT + ((size_t)b * 256 + srow) * 65536 + swoff;

#define VT_TILE(t) (Bsrc + (size_t)(pg * 2 + ((t) >> 2)) * 256 \
                         + (size_t)(((t) & 3) * 64) * 65536)

        sgk_stage512(VT_TILE(0), 65536, Bb[0], tid);

        for (int t = 0; t < 8; t++) {
            if (t + 1 < 8)
                sgk_stage512(VT_TILE(t + 1), 65536, Bb[(t + 1) & 1], tid);
            if (t == 0)     { WAIT_VM(4); }
            else if (t < 7) { WAIT_VM(12); }
            else            { WAIT_VM(8); }
            SCHED0(); BAR(); SCHED0();
            PRIO1();
            f32x4 acc[2][4];
            sgk_mfma2(Bb[t & 1], af, acc, lg, lr);
            PRIO0();

            const int p = pg * 2 + (t >> 2);
            const int sb = (t & 3) * 64;
#pragma unroll
            for (int m = 0; m < 2; m++) {
#pragma unroll
                for (int rr = 0; rr < 4; rr++) {
                    int o = wm + m * 16 + lg * 4 + rr;    // h*32+dd
                    size_t base = (size_t)(b * 8 + (o >> 5)) * 2097152
                                + (size_t)(p * 32 + (o & 31)) * 256 + sb + lr * 4;
                    s16x4 pk = {(short)f2bf(acc[m][0][rr]), (short)f2bf(acc[m][1][rr]),
                                (short)f2bf(acc[m][2][rr]), (short)f2bf(acc[m][3][rr])};
                    *(s16x4*)(Vt + base) = pk;
                }
            }
            SCHED0(); BAR(); SCHED0();
        }
#undef VT_TILE
    }
}

// ===========================================================================
// k_avT: SA = P V, 512 threads (8 waves x 32 q-rows) -> SAT [bs][p][cperm].
// grid 512: bid = nsl*32 + bh  (same-bh blocks share bid%8 -> same XCD ->
// the 128 KB P[bh] A-slice becomes L2-resident).  L=4, S=16 -> 4/20/16.
// ===========================================================================
__global__ __launch_bounds__(512, 2) void k_avT(
    const unsigned short* __restrict__ Pb, const unsigned short* __restrict__ Vt,
    unsigned short* __restrict__ SAT)
{
    const int nsl = blockIdx.x >> 5, bh = blockIdx.x & 31;
    const int b = bh >> 3, h = bh & 7;

    __shared__ __align__(16) unsigned short Bb[2][16384];

    SGK_SETUP();
    const int wm = w * 32;

    s16x8 af[2][8];
    sgk_loadA2(Pb + (size_t)bh * 65536, af, wm, lg, lr);

    const unsigned short* Bsrc = Vt + (size_t)bh * 2097152
                               + (size_t)(nsl * 512) * 256 + srow * 256 + swoff;

    sgk_stage512(Bsrc, 256, Bb[0], tid);

    for (int t = 0; t < 8; t++) {
        if (t + 1 < 8)
            sgk_stage512(Bsrc + (size_t)(t + 1) * 16384, 256, Bb[(t + 1) & 1], tid);
        if (t == 0)     { WAIT_VM(4); }
        else if (t < 7) { WAIT_VM(20); }
        else            { WAIT_VM(16); }
        SCHED0(); BAR(); SCHED0();
        PRIO1();
        f32x4 acc[2][4];
        sgk_mfma2(Bb[t & 1], af, acc, lg, lr);
        PRIO0();

        const int fb = nsl * 512 + t * 64;
        const int p0 = fb >> 5;
#pragma unroll
        for (int m = 0; m < 2; m++) {
#pragma unroll
            for (int rr = 0; rr < 4; rr++) {
                int q = wm + m * 16 + lg * 4 + rr;
                size_t base = (size_t)(b * 256 + q) * 65536
                            + (size_t)p0 * 256 + h * 32 + lr * 2;
                unsigned int v01 = (unsigned int)f2bf(acc[m][0][rr])
                                 | ((unsigned int)f2bf(acc[m][1][rr]) << 16);
                unsigned int v23 = (unsigned int)f2bf(acc[m][2][rr])
                                 | ((unsigned int)f2bf(acc[m][3][rr]) << 16);
                *(unsigned int*)(SAT + base) = v01;
                *(unsigned int*)(SAT + base + 256) = v23;
            }
        }
        SCHED0(); BAR(); SCHED0();
    }
}

// ===========================================================================
// k_outT: out = W_out SAT^T + bias, 512 threads (8 waves x 32 o-rows).
// grid 512: 2 tokens/block.  L=4, S=32 -> waits 4 / 36 / 32.
// ===========================================================================
__global__ __launch_bounds__(512, 2) void k_outT(
    const unsigned short* __restrict__ SAT, const unsigned short* __restrict__ Wbf,
    const float* __restrict__ bias, float* __restrict__ out)
{
    const int g = blockIdx.x;

    __shared__ __align__(16) unsigned short Bb[2][16384];

    SGK_SETUP();
    const int wm = w * 32;

    s16x8 af[2][8];
    sgk_loadA2(Wbf + 196608, af, wm, lg, lr);

    float bo[2][4];
#pragma unroll
    for (int m = 0; m < 2; m++)
#pragma unroll
        for (int rr = 0; rr < 4; rr++)
            bo[m][rr] = bias[wm + m * 16 + lg * 4 + rr];

    const unsigned short* Bsrc = SAT + (size_t)g * 131072 + srow * 256 + swoff;

    sgk_stage512(Bsrc, 256, Bb[0], tid);

    for (int t = 0; t < 8; t++) {
        if (t + 1 < 8)
            sgk_stage512(Bsrc + (size_t)(t + 1) * 16384, 256, Bb[(t + 1) & 1], tid);
        if (t == 0)     { WAIT_VM(4); }
        else if (t < 7) { WAIT_VM(36); }
        else            { WAIT_VM(32); }
        SCHED0(); BAR(); SCHED0();
        PRIO1();
        f32x4 acc[2][4];
        sgk_mfma2(Bb[t & 1], af, acc, lg, lr);
        PRIO0();

        const int bs = g * 2 + (t >> 2);
        const int pb = (t & 3) * 64;
#pragma unroll
        for (int m = 0; m < 2; m++) {
#pragma unroll
            for (int rr = 0; rr < 4; rr++) {
                int o = wm + m * 16 + lg * 4 + rr;
                float* d = out + ((size_t)bs * 256 + o) * 256 + pb + lr;
#pragma unroll
                for (int n = 0; n < 4; n++)
                    d[n * 16] = acc[m][n][rr] + bo[m][rr];
            }
        }
        SCHED0(); BAR(); SCHED0();
    }
}

// ===========================================================================
// k_scores: Q K^T partials (dbuf, K=8192, counted vmcnt, no in-loop stores).
// grid 512 (1D, relabeled): bid = ms*128 + bh*4 + kc.
// ===========================================================================
DI void cls_stage(const unsigned short* gp, size_t stride,
                  unsigned short* lbase, int w) {
#pragma unroll
    for (int i = 0; i < 4; i++)
        GLOAD16(gp + (size_t)(i * 8) * stride, lbase + (w * 4 + i) * 512);
}

DI void cls_mfma(const unsigned short* __restrict__ Al,
                 const unsigned short* __restrict__ Bl,
                 f32x4 acc[4][4], int wm, int wn, int lg, int lr) {
#pragma unroll
    for (int kk = 0; kk < 2; kk++) {
        int off = (((kk * 4 + lg) ^ (lr & 7)) << 3);
        s16x8 af[4];
#pragma unroll
        for (int m = 0; m < 4; m++)
            af[m] = *(const s16x8*)&Al[(wm + m * 16 + lr) * 64 + off];
        s16x8 bf[4];
#pragma unroll
        for (int n = 0; n < 4; n++)
            bf[n] = *(const s16x8*)&Bl[(wn + n * 16 + lr) * 64 + off];
#pragma unroll
        for (int n = 0; n < 4; n++) {
            bf16x8 bv = asbf(bf[n]);
#pragma unroll
            for (int m = 0; m < 4; m++)
                acc[m][n] = MFMA16(asbf(af[m]), bv, acc[m][n]);
        }
    }
}

__global__ __launch_bounds__(256, 2) void k_scores(
    const unsigned short* __restrict__ Qb, const unsigned short* __restrict__ Kb,
    float* __restrict__ Sp)
{
    const int bid = blockIdx.x;
    const int ms = bid >> 7, rem = bid & 127;
    const int bh = rem >> 2, kc = rem & 3;
    const int mt = ms >> 1, st = ms & 1;
    const int tid = threadIdx.x, ln = tid & 63, w = tid >> 6;
    const int wm = (w >> 1) * 64, wn = (w & 1) * 64;
    const int lg = ln >> 4, lr = ln & 15;
    const int srow = ln >> 3;
    const int schk = (ln & 7) ^ srow;

    __shared__ __align__(16) unsigned short Ab[2][8192];
    __shared__ __align__(16) unsigned short Bb[2][8192];

    f32x4 acc[4][4];
    const f32x4 z4 = {0.f, 0.f, 0.f, 0.f};
#pragma unroll
    for (int m = 0; m < 4; m++)
#pragma unroll
        for (int n = 0; n < 4; n++) acc[m][n] = z4;

    const unsigned short* gA = Qb + (size_t)(bh * 256 + mt * 128 + w * 32 + srow) * 8192
                             + kc * 2048 + schk * 8;
    const unsigned short* gB = Kb + (size_t)(bh * 256 + st * 128 + w * 32 + srow) * 8192
                             + kc * 2048 + schk * 8;

    cls_stage(gA, 8192, Ab[0], w);
    cls_stage(gB, 8192, Bb[0], w);

    for (int t = 0; t < 32; t++) {
        if (t + 1 < 32) {
            cls_stage(gA + (size_t)(t + 1) * 64, 8192, Ab[(t + 1) & 1], w);
            cls_stage(gB + (size_t)(t + 1) * 64, 8192, Bb[(t + 1) & 1], w);
            WAIT_VM(8);
        } else {
            WAIT_VM(0);
        }
        SCHED0(); BAR(); SCHED0();
        PRIO1();
        cls_mfma(Ab[t & 1], Bb[t & 1], acc, wm, wn, lg, lr);
        PRIO0();
        SCHED0(); BAR(); SCHED0();
    }

    float* dst = Sp + (size_t)kc * 2097152
               + (size_t)(bh * 256 + mt * 128 + wm) * 256 + st * 128 + wn;
#pragma unroll
    for (int m = 0; m < 4; m++) {
#pragma unroll
        for (int rr = 0; rr < 4; rr++) {
            float* d = dst + (size_t)(m * 16 + lg * 4 + rr) * 256 + lr;
#pragma unroll
            for (int n = 0; n < 4; n++)
                d[n * 16] = acc[m][n][rr];
        }
    }
}

// ===========================================================================
// k_softmax: sum 4 partials, scale, softmax -> P bf16, s-axis sigma-permuted
// (pos = blk*64 + (w&15)*4 + (w>>4), w = ks&63) to match Vt.  grid 2048 x 256.
// ===========================================================================
__global__ __launch_bounds__(256) void k_softmax(
    const float* __restrict__ Sp, unsigned short* __restrict__ Pb)
{
    const int tid = threadIdx.x, ln = tid & 63;
    const int row = blockIdx.x * 4 + (tid >> 6);
    const float scale = 0.011048543456039806f;  // 1/sqrt(32*256)

    const float* p0 = Sp + (size_t)row * 256 + ln * 4;
    f32x4 v = *(const f32x4*)p0;
#pragma unroll
    for (int k = 1; k < 4; k++)
        v += *(const f32x4*)(p0 + (size_t)k * 2097152);
    v *= scale;

    float m = fmaxf(fmaxf(v.x, v.y), fmaxf(v.z, v.w));
#pragma unroll
    for (int off = 32; off; off >>= 1) m = fmaxf(m, __shfl_xor(m, off));
    float e[4];
    e[0] = __expf(v.x - m); e[1] = __expf(v.y - m);
    e[2] = __expf(v.z - m); e[3] = __expf(v.w - m);
    float sum = e[0] + e[1] + e[2] + e[3];
#pragma unroll
    for (int off = 32; off; off >>= 1) sum += __shfl_xor(sum, off);
    float inv = 1.f / sum;

    unsigned short* dst = Pb + (size_t)row * 256;
#pragma unroll
    for (int j = 0; j < 4; j++) {
        int ks = ln * 4 + j;
        int wv64 = ks & 63;
        int pos = (ks & ~63) | (((wv64 & 15) << 2) + (wv64 >> 4));
        dst[pos] = f2bf(e[j] * inv);
    }
}

// ---------------------------------------------------------------------------
extern "C" void kernel_launch(void* const* d_in, const int* in_sizes, int n_in,
                              void* d_out, int out_size, void* d_ws, size_t ws_size,
                              hipStream_t stream)
{
    const float* seq  = (const float*)d_in[0];
    const float* Wqkv = (const float*)d_in[1];
    const float* Wout = (const float*)d_in[2];
    const float* bout = (const float*)d_in[3];

    // d_out: Q | K (dead before k_outT writes the final f32 output at base)
    unsigned short* Qb = (unsigned short*)d_out;
    unsigned short* Kb = Qb + 67108864;

    // d_ws: Vt | R (seqT -> Sp -> SAT) | Pb | Wbf
    unsigned short* Vt   = (unsigned short*)d_ws;
    unsigned short* seqT = Vt + 67108864;
    float*          Sp   = (float*)seqT;
    unsigned short* SAT  = seqT;
    unsigned short* Pb   = (unsigned short*)d_ws + 134217728;
    unsigned short* Wbf  = Pb + 2097152;

    float* out = (float*)d_out;

    k_tr<<<dim3(1024), dim3(256), 0, stream>>>(seq, Wqkv, Wout, seqT, Wbf);
    k_proj<<<dim3(768), dim3(512), 0, stream>>>(seqT, Wbf, Qb, Kb, Vt);
    k_scores<<<dim3(512), dim3(256), 0, stream>>>(Qb, Kb, Sp);
    k_softmax<<<dim3(2048), dim3(256), 0, stream>>>(Sp, Pb);
    k_avT<<<dim3(512), dim3(512), 0, stream>>>(Pb, Vt, SAT);
    k_outT<<<dim3(512), dim3(512), 0, stream>>>(SAT, Wbf, bout, out);
}

// Round 17
// 488.030 us; speedup vs baseline: 1.0158x; 1.0158x over previous
//
#include <hip/hip_runtime.h>
#include <stdint.h>

// FuncSelfAttention: b=4, s=256, E=256, H=8, d=32, p=16x16=256
// FINAL (round 17) = exact round-13/15 configuration, twice verified at
// 488 us / absmax 0.015625.  Round 16's k_avT relabel regressed (495.7) and
// is reverted here.  This is the terminal kernel: remaining gap to the
// ~450-470 us traffic+launch floor is below the loop's reliable-win
// resolution (all further levers A/B'd to null/negative/fail).
//
// d_out: Qb 128MiB | Kb 128MiB (dead before k_outT writes 256MiB f32 at base)
// d_ws : Vt 128MiB | R 128MiB (seqT -> Sp -> SAT) | Pb 4MiB | Wbf 0.5MiB

#define DI __device__ __forceinline__

typedef __attribute__((ext_vector_type(4))) float  f32x4;
typedef __attribute__((ext_vector_type(8))) short  s16x8;
typedef __attribute__((ext_vector_type(4))) short  s16x4;
typedef __attribute__((ext_vector_type(8))) __bf16 bf16x8;

DI unsigned short f2bf(float f) {
    unsigned int u = __builtin_bit_cast(unsigned int, f);
    u = (u + 0x7fffu + ((u >> 16) & 1u)) >> 16;
    return (unsigned short)u;
}
DI bf16x8 asbf(s16x8 v) { return __builtin_bit_cast(bf16x8, v); }
#define MFMA16(a, b, c) __builtin_amdgcn_mfma_f32_16x16x32_bf16((a), (b), (c), 0, 0, 0)

#define GLOAD16(g, l) __builtin_amdgcn_global_load_lds( \
    (const __attribute__((address_space(1))) unsigned int*)(g), \
    (__attribute__((address_space(3))) unsigned int*)(l), 16, 0, 0)

#define WAIT_VM(N) asm volatile("s_waitcnt vmcnt(" #N ")" ::: "memory")
#define BAR()    __builtin_amdgcn_s_barrier()
#define SCHED0() __builtin_amdgcn_sched_barrier(0)
#define PRIO1()  __builtin_amdgcn_s_setprio(1)
#define PRIO0()  __builtin_amdgcn_s_setprio(0)

// ===========================================================================
// Stream-GEMM building blocks
// ===========================================================================

DI void sgk_loadA4(const unsigned short* __restrict__ Asrc,
                   s16x8 af[4][8], int wm, int lg, int lr) {
#pragma unroll
    for (int m = 0; m < 4; m++)
#pragma unroll
        for (int kf = 0; kf < 8; kf++)
            af[m][kf] = *(const s16x8*)(Asrc + (size_t)(wm + m * 16 + lr) * 256
                                        + kf * 32 + lg * 8);
}
DI void sgk_loadA2(const unsigned short* __restrict__ Asrc,
                   s16x8 af[2][8], int wm, int lg, int lr) {
#pragma unroll
    for (int m = 0; m < 2; m++)
#pragma unroll
        for (int kf = 0; kf < 8; kf++)
            af[m][kf] = *(const s16x8*)(Asrc + (size_t)(wm + m * 16 + lr) * 256
                                        + kf * 32 + lg * 8);
}

// Stage one B-tile [64 n x 256 k] (32KB) with 512 threads: 4 gloads/thread.
DI void sgk_stage512(const unsigned short* src, size_t rstride,
                     unsigned short* lds, int tid) {
#pragma unroll
    for (int i = 0; i < 4; i++)
        GLOAD16(src + (size_t)(i * 16) * rstride, lds + ((i * 512 + tid) << 3));
}

DI void sgk_mfma4(const unsigned short* __restrict__ Bl,
                  const s16x8 af[4][8], f32x4 acc[4][4], int lg, int lr) {
    const f32x4 z4 = {0.f, 0.f, 0.f, 0.f};
    {
        s16x8 bfv[4];
#pragma unroll
        for (int n = 0; n < 4; n++)
            bfv[n] = *(const s16x8*)&Bl[(n * 16 + lr) * 256 + ((lg ^ (lr & 7)) << 3)];
#pragma unroll
        for (int n = 0; n < 4; n++) {
            bf16x8 bv = asbf(bfv[n]);
#pragma unroll
            for (int m = 0; m < 4; m++)
                acc[m][n] = MFMA16(asbf(af[m][0]), bv, z4);
        }
    }
#pragma unroll
    for (int kf = 1; kf < 8; kf++) {
        s16x8 bfv[4];
#pragma unroll
        for (int n = 0; n < 4; n++)
            bfv[n] = *(const s16x8*)&Bl[(n * 16 + lr) * 256
                                        + (((kf * 4 + lg) ^ (lr & 7)) << 3)];
#pragma unroll
        for (int n = 0; n < 4; n++) {
            bf16x8 bv = asbf(bfv[n]);
#pragma unroll
            for (int m = 0; m < 4; m++)
                acc[m][n] = MFMA16(asbf(af[m][kf]), bv, acc[m][n]);
        }
    }
}

DI void sgk_mfma2(const unsigned short* __restrict__ Bl,
                  const s16x8 af[2][8], f32x4 acc[2][4], int lg, int lr) {
    const f32x4 z4 = {0.f, 0.f, 0.f, 0.f};
    {
        s16x8 bfv[4];
#pragma unroll
        for (int n = 0; n < 4; n++)
            bfv[n] = *(const s16x8*)&Bl[(n * 16 + lr) * 256 + ((lg ^ (lr & 7)) << 3)];
#pragma unroll
        for (int n = 0; n < 4; n++) {
            bf16x8 bv = asbf(bfv[n]);
#pragma unroll
            for (int m = 0; m < 2; m++)
                acc[m][n] = MFMA16(asbf(af[m][0]), bv, z4);
        }
    }
#pragma unroll
    for (int kf = 1; kf < 8; kf++) {
        s16x8 bfv[4];
#pragma unroll
        for (int n = 0; n < 4; n++)
            bfv[n] = *(const s16x8*)&Bl[(n * 16 + lr) * 256
                                        + (((kf * 4 + lg) ^ (lr & 7)) << 3)];
#pragma unroll
        for (int n = 0; n < 4; n++) {
            bf16x8 bv = asbf(bfv[n]);
#pragma unroll
            for (int m = 0; m < 2; m++)
                acc[m][n] = MFMA16(asbf(af[m][kf]), bv, acc[m][n]);
        }
    }
}

#define SGK_SETUP()                                           \
    const int tid = threadIdx.x, ln = tid & 63, w = tid >> 6; \
    const int lg = ln >> 4, lr = ln & 15;                     \
    const size_t swoff = (size_t)(((tid & 31) ^ ((tid >> 5) & 7)) * 8); \
    const size_t srow = (size_t)(tid >> 5);

// ===========================================================================
// k_tr: seq f32 [bs][256 c][256 p] -> seqT bf16 [bs][256 p][256 c],
// PLUS prep of Wbf row r = blockIdx.x (W_qkv split-major permuted rows;
// W_out rows with columns permuted to SAT's channel order).
// ===========================================================================
__global__ __launch_bounds__(256) void k_tr(
    const float* __restrict__ seq, const float* __restrict__ Wqkv,
    const float* __restrict__ Wout, unsigned short* __restrict__ seqT,
    unsigned short* __restrict__ Wbf)
{
    const int bs = blockIdx.x, tid = threadIdx.x;

    {   // folded k_prep: one Wbf row per block, one element per thread
        int r = bs, c = tid;
        float v;
        if (r < 768) {
            int split = r >> 8, hd = r & 255;
            v = Wqkv[(size_t)(((hd >> 5) * 96) + split * 32 + (hd & 31)) * 256 + c];
        } else {
            int jj = c & 31;
            int dd = (jj >> 1) + ((jj & 1) << 4);   // inverse of (dd&15)*2+(dd>>4)
            v = Wout[(size_t)(r - 768) * 256 + (c & ~31) + dd];
        }
        Wbf[(size_t)r * 256 + c] = f2bf(v);
    }

    __shared__ __align__(16) unsigned short T[64][264];
    const float* src = seq + (size_t)bs * 65536;
    unsigned short* dst = seqT + (size_t)bs * 65536;

    for (int co = 0; co < 256; co += 64) {
        {
            int r = tid >> 2, p0 = (tid & 3) * 64;
            const float* s = src + (size_t)(co + r) * 256 + p0;
#pragma unroll
            for (int i = 0; i < 8; i++) {
                f32x4 a = *(const f32x4*)(s + i * 8);
                f32x4 b = *(const f32x4*)(s + i * 8 + 4);
                s16x8 h = {(short)f2bf(a.x), (short)f2bf(a.y), (short)f2bf(a.z),
                           (short)f2bf(a.w), (short)f2bf(b.x), (short)f2bf(b.y),
                           (short)f2bf(b.z), (short)f2bf(b.w)};
                *(s16x8*)&T[r][p0 + i * 8] = h;
            }
        }
        __syncthreads();
        {
            unsigned short e[64];
#pragma unroll
            for (int c = 0; c < 64; c++) e[c] = T[c][tid];
            unsigned short* d = dst + (size_t)tid * 256 + co;
#pragma unroll
            for (int j = 0; j < 8; j++) {
                s16x8 v = {(short)e[j * 8 + 0], (short)e[j * 8 + 1],
                           (short)e[j * 8 + 2], (short)e[j * 8 + 3],
                           (short)e[j * 8 + 4], (short)e[j * 8 + 5],
                           (short)e[j * 8 + 6], (short)e[j * 8 + 7]};
                *(s16x8*)(d + j * 8) = v;
            }
        }
        __syncthreads();
    }
}

// ===========================================================================
// k_proj: merged Q/K projection (bid < 256) and V projection (bid >= 256).
// QK: 8 waves x 64 rows (Q||K), 16 tiles, L=4 S=16 -> waits 4/20/16.
//     Q/K feature layout psw = pb + lr*4 + n.
// V : 8 waves x 32 rows, 8 tiles, L=4 S=8 -> waits 4/12/8.
//     Vt[bh][p*32+dd][ssw], ssw = sb + lr*4 + n (sigma-permuted s-axis).
// ===========================================================================
__global__ __launch_bounds__(512, 2) void k_proj(
    const unsigned short* __restrict__ seqT, const unsigned short* __restrict__ Wbf,
    unsigned short* __restrict__ Qb, unsigned short* __restrict__ Kb,
    unsigned short* __restrict__ Vt)
{
    __shared__ __align__(16) unsigned short Bb[2][16384];

    SGK_SETUP();

    if (blockIdx.x < 256) {
        // ---------------- QK path ----------------
        const int g = blockIdx.x;
        const int wm = w * 64;

        s16x8 af[4][8];
        sgk_loadA4(Wbf, af, wm, lg, lr);   // rows 0..511 = Q||K

        const unsigned short* Bsrc = seqT + (size_t)g * 262144 + srow * 256 + swoff;
        unsigned short* const dstB = (w >= 4) ? Kb : Qb;

        sgk_stage512(Bsrc, 256, Bb[0], tid);

        for (int t = 0; t < 16; t++) {
            if (t + 1 < 16)
                sgk_stage512(Bsrc + (size_t)(t + 1) * 16384, 256, Bb[(t + 1) & 1], tid);
            if (t == 0)      { WAIT_VM(4); }
            else if (t < 15) { WAIT_VM(20); }
            else             { WAIT_VM(16); }
            SCHED0(); BAR(); SCHED0();
            PRIO1();
            f32x4 acc[4][4];
            sgk_mfma4(Bb[t & 1], af, acc, lg, lr);
            PRIO0();

            const int bs = g * 4 + (t >> 2);
            const int b = bs >> 8, s = bs & 255;
            const int pb = (t & 3) * 64;
#pragma unroll
            for (int m = 0; m < 4; m++) {
#pragma unroll
                for (int rr = 0; rr < 4; rr++) {
                    int oo = wm + m * 16 + lg * 4 + rr;   // 0..511
                    int o = oo & 255;
                    size_t base = ((size_t)((b * 8 + (o >> 5)) * 256 + s)) * 8192
                                + (size_t)(o & 31) * 256 + pb + lr * 4;
                    s16x4 pk = {(short)f2bf(acc[m][0][rr]), (short)f2bf(acc[m][1][rr]),
                                (short)f2bf(acc[m][2][rr]), (short)f2bf(acc[m][3][rr])};
                    *(s16x4*)(dstB + base) = pk;
                }
            }
            SCHED0(); BAR(); SCHED0();
        }
    } else {
        // ---------------- V path ----------------
        const int x = blockIdx.x - 256;
        const int b = x >> 7, pg = x & 127;
        const int wm = w * 32;

        s16x8 af[2][8];
        sgk_loadA2(Wbf + 131072, af, wm, lg, lr);

        const unsigned short* Bsrc = seqT + ((size_t)b * 256 + srow) * 65536 + swoff;

#define VT_TILE(t) (Bsrc + (size_t)(pg * 2 + ((t) >> 2)) * 256 \
                         + (size_t)(((t) & 3) * 64) * 65536)

        sgk_stage512(VT_TILE(0), 65536, Bb[0], tid);

        for (int t = 0; t < 8; t++) {
            if (t + 1 < 8)
                sgk_stage512(VT_TILE(t + 1), 65536, Bb[(t + 1) & 1], tid);
            if (t == 0)     { WAIT_VM(4); }
            else if (t < 7) { WAIT_VM(12); }
            else            { WAIT_VM(8); }
            SCHED0(); BAR(); SCHED0();
            PRIO1();
            f32x4 acc[2][4];
            sgk_mfma2(Bb[t & 1], af, acc, lg, lr);
            PRIO0();

            const int p = pg * 2 + (t >> 2);
            const int sb = (t & 3) * 64;
#pragma unroll
            for (int m = 0; m < 2; m++) {
#pragma unroll
                for (int rr = 0; rr < 4; rr++) {
                    int o = wm + m * 16 + lg * 4 + rr;    // h*32+dd
                    size_t base = (size_t)(b * 8 + (o >> 5)) * 2097152
                                + (size_t)(p * 32 + (o & 31)) * 256 + sb + lr * 4;
                    s16x4 pk = {(short)f2bf(acc[m][0][rr]), (short)f2bf(acc[m][1][rr]),
                                (short)f2bf(acc[m][2][rr]), (short)f2bf(acc[m][3][rr])};
                    *(s16x4*)(Vt + base) = pk;
                }
            }
            SCHED0(); BAR(); SCHED0();
        }
#undef VT_TILE
    }
}

// ===========================================================================
// k_avT: SA = P V, 512 threads (8 waves x 32 q-rows) -> SAT [bs][p][cperm].
// grid 512: x = bh*16 + nsl.  L=4, S=16 -> waits 4 / 20 / 16.
// ===========================================================================
__global__ __launch_bounds__(512, 2) void k_avT(
    const unsigned short* __restrict__ Pb, const unsigned short* __restrict__ Vt,
    unsigned short* __restrict__ SAT)
{
    const int bh = blockIdx.x >> 4, nsl = blockIdx.x & 15;
    const int b = bh >> 3, h = bh & 7;

    __shared__ __align__(16) unsigned short Bb[2][16384];

    SGK_SETUP();
    const int wm = w * 32;

    s16x8 af[2][8];
    sgk_loadA2(Pb + (size_t)bh * 65536, af, wm, lg, lr);

    const unsigned short* Bsrc = Vt + (size_t)bh * 2097152
                               + (size_t)(nsl * 512) * 256 + srow * 256 + swoff;

    sgk_stage512(Bsrc, 256, Bb[0], tid);

    for (int t = 0; t < 8; t++) {
        if (t + 1 < 8)
            sgk_stage512(Bsrc + (size_t)(t + 1) * 16384, 256, Bb[(t + 1) & 1], tid);
        if (t == 0)     { WAIT_VM(4); }
        else if (t < 7) { WAIT_VM(20); }
        else            { WAIT_VM(16); }
        SCHED0(); BAR(); SCHED0();
        PRIO1();
        f32x4 acc[2][4];
        sgk_mfma2(Bb[t & 1], af, acc, lg, lr);
        PRIO0();

        const int fb = nsl * 512 + t * 64;
        const int p0 = fb >> 5;
#pragma unroll
        for (int m = 0; m < 2; m++) {
#pragma unroll
            for (int rr = 0; rr < 4; rr++) {
                int q = wm + m * 16 + lg * 4 + rr;
                size_t base = (size_t)(b * 256 + q) * 65536
                            + (size_t)p0 * 256 + h * 32 + lr * 2;
                unsigned int v01 = (unsigned int)f2bf(acc[m][0][rr])
                                 | ((unsigned int)f2bf(acc[m][1][rr]) << 16);
                unsigned int v23 = (unsigned int)f2bf(acc[m][2][rr])
                                 | ((unsigned int)f2bf(acc[m][3][rr]) << 16);
                *(unsigned int*)(SAT + base) = v01;
                *(unsigned int*)(SAT + base + 256) = v23;
            }
        }
        SCHED0(); BAR(); SCHED0();
    }
}

// ===========================================================================
// k_outT: out = W_out SAT^T + bias, 512 threads (8 waves x 32 o-rows).
// grid 512: 2 tokens/block.  L=4, S=32 -> waits 4 / 36 / 32.
// ===========================================================================
__global__ __launch_bounds__(512, 2) void k_outT(
    const unsigned short* __restrict__ SAT, const unsigned short* __restrict__ Wbf,
    const float* __restrict__ bias, float* __restrict__ out)
{
    const int g = blockIdx.x;

    __shared__ __align__(16) unsigned short Bb[2][16384];

    SGK_SETUP();
    const int wm = w * 32;

    s16x8 af[2][8];
    sgk_loadA2(Wbf + 196608, af, wm, lg, lr);

    float bo[2][4];
#pragma unroll
    for (int m = 0; m < 2; m++)
#pragma unroll
        for (int rr = 0; rr < 4; rr++)
            bo[m][rr] = bias[wm + m * 16 + lg * 4 + rr];

    const unsigned short* Bsrc = SAT + (size_t)g * 131072 + srow * 256 + swoff;

    sgk_stage512(Bsrc, 256, Bb[0], tid);

    for (int t = 0; t < 8; t++) {
        if (t + 1 < 8)
            sgk_stage512(Bsrc + (size_t)(t + 1) * 16384, 256, Bb[(t + 1) & 1], tid);
        if (t == 0)     { WAIT_VM(4); }
        else if (t < 7) { WAIT_VM(36); }
        else            { WAIT_VM(32); }
        SCHED0(); BAR(); SCHED0();
        PRIO1();
        f32x4 acc[2][4];
        sgk_mfma2(Bb[t & 1], af, acc, lg, lr);
        PRIO0();

        const int bs = g * 2 + (t >> 2);
        const int pb = (t & 3) * 64;
#pragma unroll
        for (int m = 0; m < 2; m++) {
#pragma unroll
            for (int rr = 0; rr < 4; rr++) {
                int o = wm + m * 16 + lg * 4 + rr;
                float* d = out + ((size_t)bs * 256 + o) * 256 + pb + lr;
#pragma unroll
                for (int n = 0; n < 4; n++)
                    d[n * 16] = acc[m][n][rr] + bo[m][rr];
            }
        }
        SCHED0(); BAR(); SCHED0();
    }
}

// ===========================================================================
// k_scores: Q K^T partials (dbuf, K=8192, counted vmcnt, no in-loop stores).
// grid 512 (1D, relabeled): bid = ms*128 + bh*4 + kc.
// ===========================================================================
DI void cls_stage(const unsigned short* gp, size_t stride,
                  unsigned short* lbase, int w) {
#pragma unroll
    for (int i = 0; i < 4; i++)
        GLOAD16(gp + (size_t)(i * 8) * stride, lbase + (w * 4 + i) * 512);
}

DI void cls_mfma(const unsigned short* __restrict__ Al,
                 const unsigned short* __restrict__ Bl,
                 f32x4 acc[4][4], int wm, int wn, int lg, int lr) {
#pragma unroll
    for (int kk = 0; kk < 2; kk++) {
        int off = (((kk * 4 + lg) ^ (lr & 7)) << 3);
        s16x8 af[4];
#pragma unroll
        for (int m = 0; m < 4; m++)
            af[m] = *(const s16x8*)&Al[(wm + m * 16 + lr) * 64 + off];
        s16x8 bf[4];
#pragma unroll
        for (int n = 0; n < 4; n++)
            bf[n] = *(const s16x8*)&Bl[(wn + n * 16 + lr) * 64 + off];
#pragma unroll
        for (int n = 0; n < 4; n++) {
            bf16x8 bv = asbf(bf[n]);
#pragma unroll
            for (int m = 0; m < 4; m++)
                acc[m][n] = MFMA16(asbf(af[m]), bv, acc[m][n]);
        }
    }
}

__global__ __launch_bounds__(256, 2) void k_scores(
    const unsigned short* __restrict__ Qb, const unsigned short* __restrict__ Kb,
    float* __restrict__ Sp)
{
    const int bid = blockIdx.x;
    const int ms = bid >> 7, rem = bid & 127;
    const int bh = rem >> 2, kc = rem & 3;
    const int mt = ms >> 1, st = ms & 1;
    const int tid = threadIdx.x, ln = tid & 63, w = tid >> 6;
    const int wm = (w >> 1) * 64, wn = (w & 1) * 64;
    const int lg = ln >> 4, lr = ln & 15;
    const int srow = ln >> 3;
    const int schk = (ln & 7) ^ srow;

    __shared__ __align__(16) unsigned short Ab[2][8192];
    __shared__ __align__(16) unsigned short Bb[2][8192];

    f32x4 acc[4][4];
    const f32x4 z4 = {0.f, 0.f, 0.f, 0.f};
#pragma unroll
    for (int m = 0; m < 4; m++)
#pragma unroll
        for (int n = 0; n < 4; n++) acc[m][n] = z4;

    const unsigned short* gA = Qb + (size_t)(bh * 256 + mt * 128 + w * 32 + srow) * 8192
                             + kc * 2048 + schk * 8;
    const unsigned short* gB = Kb + (size_t)(bh * 256 + st * 128 + w * 32 + srow) * 8192
                             + kc * 2048 + schk * 8;

    cls_stage(gA, 8192, Ab[0], w);
    cls_stage(gB, 8192, Bb[0], w);

    for (int t = 0; t < 32; t++) {
        if (t + 1 < 32) {
            cls_stage(gA + (size_t)(t + 1) * 64, 8192, Ab[(t + 1) & 1], w);
            cls_stage(gB + (size_t)(t + 1) * 64, 8192, Bb[(t + 1) & 1], w);
            WAIT_VM(8);
        } else {
            WAIT_VM(0);
        }
        SCHED0(); BAR(); SCHED0();
        PRIO1();
        cls_mfma(Ab[t & 1], Bb[t & 1], acc, wm, wn, lg, lr);
        PRIO0();
        SCHED0(); BAR(); SCHED0();
    }

    float* dst = Sp + (size_t)kc * 2097152
               + (size_t)(bh * 256 + mt * 128 + wm) * 256 + st * 128 + wn;
#pragma unroll
    for (int m = 0; m < 4; m++) {
#pragma unroll
        for (int rr = 0; rr < 4; rr++) {
            float* d = dst + (size_t)(m * 16 + lg * 4 + rr) * 256 + lr;
#pragma unroll
            for (int n = 0; n < 4; n++)
                d[n * 16] = acc[m][n][rr];
        }
    }
}

// ===========================================================================
// k_softmax: sum 4 partials, scale, softmax -> P bf16, s-axis sigma-permuted
// (pos = blk*64 + (w&15)*4 + (w>>4), w = ks&63) to match Vt.  grid 2048 x 256.
// ===========================================================================
__global__ __launch_bounds__(256) void k_softmax(
    const float* __restrict__ Sp, unsigned short* __restrict__ Pb)
{
    const int tid = threadIdx.x, ln = tid & 63;
    const int row = blockIdx.x * 4 + (tid >> 6);
    const float scale = 0.011048543456039806f;  // 1/sqrt(32*256)

    const float* p0 = Sp + (size_t)row * 256 + ln * 4;
    f32x4 v = *(const f32x4*)p0;
#pragma unroll
    for (int k = 1; k < 4; k++)
        v += *(const f32x4*)(p0 + (size_t)k * 2097152);
    v *= scale;

    float m = fmaxf(fmaxf(v.x, v.y), fmaxf(v.z, v.w));
#pragma unroll
    for (int off = 32; off; off >>= 1) m = fmaxf(m, __shfl_xor(m, off));
    float e[4];
    e[0] = __expf(v.x - m); e[1] = __expf(v.y - m);
    e[2] = __expf(v.z - m); e[3] = __expf(v.w - m);
    float sum = e[0] + e[1] + e[2] + e[3];
#pragma unroll
    for (int off = 32; off; off >>= 1) sum += __shfl_xor(sum, off);
    float inv = 1.f / sum;

    unsigned short* dst = Pb + (size_t)row * 256;
#pragma unroll
    for (int j = 0; j < 4; j++) {
        int ks = ln * 4 + j;
        int wv64 = ks & 63;
        int pos = (ks & ~63) | (((wv64 & 15) << 2) + (wv64 >> 4));
        dst[pos] = f2bf(e[j] * inv);
    }
}

// ---------------------------------------------------------------------------
extern "C" void kernel_launch(void* const* d_in, const int* in_sizes, int n_in,
                              void* d_out, int out_size, void* d_ws, size_t ws_size,
                              hipStream_t stream)
{
    const float* seq  = (const float*)d_in[0];
    const float* Wqkv = (const float*)d_in[1];
    const float* Wout = (const float*)d_in[2];
    const float* bout = (const float*)d_in[3];

    // d_out: Q | K (dead before k_outT writes the final f32 output at base)
    unsigned short* Qb = (unsigned short*)d_out;
    unsigned short* Kb = Qb + 67108864;

    // d_ws: Vt | R (seqT -> Sp -> SAT) | Pb | Wbf
    unsigned short* Vt   = (unsigned short*)d_ws;
    unsigned short* seqT = Vt + 67108864;
    float*          Sp   = (float*)seqT;
    unsigned short* SAT  = seqT;
    unsigned short* Pb   = (unsigned short*)d_ws + 134217728;
    unsigned short* Wbf  = Pb + 2097152;

    float* out = (float*)d_out;

    k_tr<<<dim3(1024), dim3(256), 0, stream>>>(seq, Wqkv, Wout, seqT, Wbf);
    k_proj<<<dim3(768), dim3(512), 0, stream>>>(seqT, Wbf, Qb, Kb, Vt);
    k_scores<<<dim3(512), dim3(256), 0, stream>>>(Qb, Kb, Sp);
    k_softmax<<<dim3(2048), dim3(256), 0, stream>>>(Sp, Pb);
    k_avT<<<dim3(512), dim3(512), 0, stream>>>(Pb, Vt, SAT);
    k_outT<<<dim3(512), dim3(512), 0, stream>>>(SAT, Wbf, bout, out);
}